// Round 7
// baseline (133.406 us; speedup 1.0000x reference)
//
#include <hip/hip_runtime.h>
#include <stdint.h>

typedef short short8 __attribute__((ext_vector_type(8)));
typedef float f32x4 __attribute__((ext_vector_type(4)));
typedef float f32x2 __attribute__((ext_vector_type(2)));

#define B_TOTAL 8192
#define DDIM 256
#define BM 256
#define BN 64
#define NSPLIT 16
#define COLS_PER (B_TOTAL / NSPLIT)        // 512
#define ITERS (COLS_PER / BN)              // 8
#define NBLOCKS ((B_TOTAL / BM) * NSPLIT)  // 512 = exactly 2 blocks/CU
// sqrt((1/T)/ln2): fold temperature+log2e into the bf16 embeddings (both operands)
#define SCALE_HALF 3.79828546f
#define LN2F 0.6931471805599453f

typedef __attribute__((address_space(3))) char lds_char;
typedef __attribute__((address_space(1))) const char gbl_char;

__device__ __forceinline__ unsigned short f2bf(float f) {
  unsigned int u = __builtin_bit_cast(unsigned int, f);
  u = (u + 0x7FFFu + ((u >> 16) & 1u)) >> 16;   // RNE; inputs are finite
  return (unsigned short)u;
}

// ---- prep: fp32->bf16 (scaled), one-hot label pack, zero accumulators -------
__global__ __launch_bounds__(256) void prep_all(
    const float* __restrict__ E, const int* __restrict__ lab,
    unsigned short* __restrict__ Eb, unsigned int* __restrict__ plab,
    float* __restrict__ posAll) {
  const int t = blockIdx.x * 256 + threadIdx.x;   // 0..262143, 8 floats each
  const float4* s4 = (const float4*)E + (size_t)t * 2;
  float4 v0 = s4[0], v1 = s4[1];
  short8 o;
  o[0] = (short)f2bf(v0.x * SCALE_HALF); o[1] = (short)f2bf(v0.y * SCALE_HALF);
  o[2] = (short)f2bf(v0.z * SCALE_HALF); o[3] = (short)f2bf(v0.w * SCALE_HALF);
  o[4] = (short)f2bf(v1.x * SCALE_HALF); o[5] = (short)f2bf(v1.y * SCALE_HALF);
  o[6] = (short)f2bf(v1.z * SCALE_HALF); o[7] = (short)f2bf(v1.w * SCALE_HALF);
  *(short8*)(Eb + (size_t)t * 8) = o;
  if (t < B_TOTAL) {
    int4 l = ((const int4*)lab)[t];   // labels arrive as int32
    // positional one-hot: aspect a (value 0..5) occupies bits [6a, 6a+6)
    plab[t] = (1u << ((unsigned)l.x & 31u))
            | (1u << (((unsigned)l.y & 31u) + 6u))
            | (1u << (((unsigned)l.z & 31u) + 12u))
            | (1u << (((unsigned)l.w & 31u) + 18u));
  }
  if (t < 2 * B_TOTAL) posAll[t] = 0.0f;   // posArr+allArr contiguous
}

// ---- fused sim/exp/mask/rowsum: BM=256 (64 rows/wave), 2-phase dbuf ---------
struct __align__(16) SMem {
  char btile[2][BN * DDIM * 2];      // 2 x 32 KB, XOR-swizzled 16B chunks
  unsigned int plab_all[COLS_PER];   // 2 KB: packed labels for the whole panel
};

// epilogue for one n-half (2 col-blocks of 16), 4 m-blocks
template <int DIAG>
__device__ __forceinline__ void do_epilogue(
    const f32x4 (&acc)[2][4], int jbase /*colbase+nh*32*/, int lbase /*it*BN+nh*32*/,
    int l15, int row0 /*rowbase+wid*64+l4*4*/,
    const unsigned int (&pi)[4][4], const unsigned int* plab_all,
    f32x2 (&pos2)[4][2], f32x2 (&all2)[4][2]) {
#pragma unroll
  for (int n2 = 0; n2 < 2; ++n2) {
    const int j = jbase + n2 * 16 + l15;
    const unsigned int hj = plab_all[lbase + n2 * 16 + l15];
#pragma unroll
    for (int m = 0; m < 4; ++m) {
      float e[4];
#pragma unroll
      for (int q = 0; q < 4; ++q) {
        float v = __builtin_amdgcn_exp2f(acc[n2][m][q]);  // acc pre-scaled
        if (DIAG) { if (j == row0 + m * 16 + q) v = 0.0f; }
        e[q] = v;
      }
      f32x2 p01 = { (pi[m][0] & hj) ? e[0] : 0.0f, (pi[m][1] & hj) ? e[1] : 0.0f };
      f32x2 p23 = { (pi[m][2] & hj) ? e[2] : 0.0f, (pi[m][3] & hj) ? e[3] : 0.0f };
      all2[m][0] += (f32x2){e[0], e[1]};
      all2[m][1] += (f32x2){e[2], e[3]};
      pos2[m][0] += p01;
      pos2[m][1] += p23;
    }
  }
}

__global__ __launch_bounds__(256, 2) void main_kernel(
    const unsigned short* __restrict__ Eb, const unsigned int* __restrict__ plab,
    float* __restrict__ posArr, float* __restrict__ allArr) {
  __shared__ SMem sm;
  const int tid = threadIdx.x;
  const int lane = tid & 63;
  const int wid = tid >> 6;        // 4 waves, each owns 64 rows
  const int l15 = lane & 15;
  const int l4 = lane >> 4;
  const int rb = (int)blockIdx.x & 31;   // 32 row-blocks of 256
  const int cs = (int)blockIdx.x >> 5;   // 16 column panels of 512
  const int rowbase = rb * BM;
  const int colstart = cs * COLS_PER;
  const int row0 = rowbase + wid * 64 + l4 * 4;   // +m*16+q = this lane's rows

  // stage helper: 32 KB B-tile, 8 x global_load_lds(16B) per thread.
  // linear LDS dest (wave-uniform base + lane*16), inverse-swizzled global src
  // (rule #21); read side applies the same XOR.
  auto stage = [&](int bufi, int cb) {
#pragma unroll
    for (int q = 0; q < 8; ++q) {
      const unsigned int L = (unsigned int)wid * 8192u + (unsigned int)q * 1024u +
                             (unsigned int)lane * 16u;
      const unsigned int r = L >> 9;          // B-tile row / output column (0..63)
      const unsigned int s = (L >> 4) & 31u;  // stored 16B chunk in row
      const unsigned int c = s ^ (r & 7u);    // logical chunk (involution)
      const char* src = (const char*)(Eb + (size_t)(cb + (int)r) * DDIM + c * 8);
      char* dst = sm.btile[bufi] + (unsigned int)wid * 8192u + (unsigned int)q * 1024u;
      __builtin_amdgcn_global_load_lds((gbl_char*)src, (lds_char*)dst, 16, 0, 0);
    }
  };

  // prologue: issue tile 0 staging first (hide L2 latency under setup below)
  stage(0, colstart);

  // A fragments: register-resident, 64 rows x 256 k per wave (128 VGPR)
  short8 afrag[4][8];
#pragma unroll
  for (int m = 0; m < 4; ++m) {
    const int row = rowbase + wid * 64 + m * 16 + l15;
    const unsigned short* rp = Eb + (size_t)row * DDIM + l4 * 8;
#pragma unroll
    for (int k = 0; k < 8; ++k) afrag[m][k] = *(const short8*)(rp + k * 32);
  }

  // panel labels -> LDS once (keeps the in-loop vmcnt count pure: stage only)
  {
    unsigned int a0 = plab[colstart + tid];
    unsigned int a1 = plab[colstart + 256 + tid];
    sm.plab_all[tid] = a0;
    sm.plab_all[tid + 256] = a1;
  }

  unsigned int pi[4][4];
#pragma unroll
  for (int m = 0; m < 4; ++m)
#pragma unroll
    for (int q = 0; q < 4; ++q) pi[m][q] = plab[row0 + m * 16 + q];

  // drain label ds_writes before first barrier (other waves read plab_all)
  asm volatile("s_waitcnt lgkmcnt(0)" ::: "memory");
  __builtin_amdgcn_sched_barrier(0);

  f32x2 pos2[4][2] = {};
  f32x2 all2[4][2] = {};

  for (int it = 0; it < ITERS; ++it) {
    const int colbase = colstart + it * BN;
    const int cur = it & 1;

    if (it + 1 < ITERS) {
      stage(cur ^ 1, colbase + BN);                     // issue next tile (8/thread)
      asm volatile("s_waitcnt vmcnt(8)" ::: "memory");  // oldest 8 (tile it) landed
    } else {
      asm volatile("s_waitcnt vmcnt(0)" ::: "memory");  // final tile: full drain
    }
    __builtin_amdgcn_s_barrier();                       // all waves' shares landed
    __builtin_amdgcn_sched_barrier(0);

    const bool hasDiag = (colbase < rowbase + BM) && (rowbase < colbase + BN);

    // two n-halves: keeps live acc at 32 VGPR; nh=1 MFMAs overlap nh=0 exp's
#pragma unroll
    for (int nh = 0; nh < 2; ++nh) {
      f32x4 acc[2][4];
#pragma unroll
      for (int n2 = 0; n2 < 2; ++n2)
#pragma unroll
        for (int m = 0; m < 4; ++m) acc[n2][m] = (f32x4){0.f, 0.f, 0.f, 0.f};

      __builtin_amdgcn_s_setprio(1);
#pragma unroll
      for (int k = 0; k < 8; ++k) {
        short8 b[2];
#pragma unroll
        for (int n2 = 0; n2 < 2; ++n2) {
          const unsigned int rr = (unsigned int)(nh * 32 + n2 * 16 + l15);
          const unsigned int cdx = (unsigned int)(k * 4 + l4);
          const unsigned int s = cdx ^ (rr & 7u);   // swizzled read
          b[n2] = *(const short8*)(sm.btile[cur] + rr * 512u + s * 16u);
        }
#pragma unroll
        for (int n2 = 0; n2 < 2; ++n2)
#pragma unroll
          for (int m = 0; m < 4; ++m)
            acc[n2][m] = __builtin_amdgcn_mfma_f32_16x16x32_bf16(
                afrag[m][k], b[n2], acc[n2][m], 0, 0, 0);
      }
      __builtin_amdgcn_s_setprio(0);

      if (hasDiag)
        do_epilogue<1>(acc, colbase + nh * 32, it * BN + nh * 32, l15, row0,
                       pi, sm.plab_all, pos2, all2);
      else
        do_epilogue<0>(acc, colbase + nh * 32, it * BN + nh * 32, l15, row0,
                       pi, sm.plab_all, pos2, all2);
    }

    __builtin_amdgcn_s_barrier();   // all waves done reading btile[cur]
    __builtin_amdgcn_sched_barrier(0);
  }

  // reduce across the 16 lanes sharing the same rows, then one atomic per row
#pragma unroll
  for (int m = 0; m < 4; ++m)
#pragma unroll
    for (int q = 0; q < 4; ++q) {
      float p = pos2[m][q >> 1][q & 1], al = all2[m][q >> 1][q & 1];
      p += __shfl_xor(p, 1); p += __shfl_xor(p, 2);
      p += __shfl_xor(p, 4); p += __shfl_xor(p, 8);
      al += __shfl_xor(al, 1); al += __shfl_xor(al, 2);
      al += __shfl_xor(al, 4); al += __shfl_xor(al, 8);
      if (l15 == 0) {
        atomicAdd(&posArr[row0 + m * 16 + q], p);
        atomicAdd(&allArr[row0 + m * 16 + q], al);
      }
    }
}

// ---- finalize: row losses + mean (separate launch = free ordering) ----------
__global__ __launch_bounds__(1024) void finalize_kernel(
    const float* __restrict__ posArr, const float* __restrict__ allArr,
    float* __restrict__ out) {
  float ls = 0.f, cnt = 0.f;
#pragma unroll
  for (int k = 0; k < B_TOTAL / 1024; ++k) {
    const int i = threadIdx.x + (k << 10);
    const float p = posArr[i];
    const float a = allArr[i];
    if (p > 0.f) {
      ls += (__builtin_amdgcn_logf(a + 1e-8f) - __builtin_amdgcn_logf(p)) * LN2F;
      cnt += 1.f;
    }
  }
#pragma unroll
  for (int msk = 1; msk < 64; msk <<= 1) {
    ls += __shfl_xor(ls, msk);
    cnt += __shfl_xor(cnt, msk);
  }
  __shared__ float sls[16], scnt[16];
  const int w = threadIdx.x >> 6;
  if ((threadIdx.x & 63) == 0) { sls[w] = ls; scnt[w] = cnt; }
  __syncthreads();
  if (threadIdx.x == 0) {
    float L = 0.f, C = 0.f;
    for (int i = 0; i < 16; ++i) { L += sls[i]; C += scnt[i]; }
    out[0] = (C > 0.f) ? L / fmaxf(C, 1.f) : 0.f;
  }
}

// ---- launch -----------------------------------------------------------------
extern "C" void kernel_launch(void* const* d_in, const int* in_sizes, int n_in,
                              void* d_out, int out_size, void* d_ws, size_t ws_size,
                              hipStream_t stream) {
  const float* E = (const float*)d_in[0];
  const int* lab = (const int*)d_in[1];
  float* out = (float*)d_out;
  char* ws = (char*)d_ws;

  unsigned short* Eb = (unsigned short*)ws;                       // 4 MB
  unsigned int* plab = (unsigned int*)(ws + 4u * 1024u * 1024u);  // 32 KB
  float* posArr = (float*)(ws + 4u * 1024u * 1024u + 32u * 1024u);
  float* allArr = posArr + B_TOTAL;

  prep_all<<<1024, 256, 0, stream>>>(E, lab, Eb, plab, posArr);
  main_kernel<<<NBLOCKS, 256, 0, stream>>>(Eb, plab, posArr, allArr);
  finalize_kernel<<<1, 1024, 0, stream>>>(posArr, allArr, out);
}

// Round 8
// 126.345 us; speedup vs baseline: 1.0559x; 1.0559x over previous
//
#include <hip/hip_runtime.h>
#include <stdint.h>

typedef short short8 __attribute__((ext_vector_type(8)));
typedef float f32x4 __attribute__((ext_vector_type(4)));
typedef float f32x2 __attribute__((ext_vector_type(2)));

#define B_TOTAL 8192
#define DDIM 256
#define TILE 128
#define NTILE (B_TOTAL / TILE)             // 64
#define NPAIRS (NTILE * (NTILE + 1) / 2)   // 2080 blocks: tiles J>=I
// sqrt((1/T)/ln2): fold temperature+log2e into the bf16 embeddings (both operands)
#define SCALE_HALF 3.79828546f
#define LN2F 0.6931471805599453f

typedef __attribute__((address_space(3))) char lds_char;
typedef __attribute__((address_space(1))) const char gbl_char;

__device__ __forceinline__ unsigned short f2bf(float f) {
  unsigned int u = __builtin_bit_cast(unsigned int, f);
  u = (u + 0x7FFFu + ((u >> 16) & 1u)) >> 16;   // RNE; inputs are finite
  return (unsigned short)u;
}

// ---- prep: fp32->bf16 (scaled), label pack, zero accumulators, tile LUT -----
__global__ __launch_bounds__(256) void prep_all(
    const float* __restrict__ E, const int* __restrict__ lab,
    unsigned short* __restrict__ Eb, unsigned int* __restrict__ plab,
    float* __restrict__ posAll, unsigned int* __restrict__ lut) {
  const int t = blockIdx.x * 256 + threadIdx.x;   // 0..262143, 8 floats each
  const float4* s4 = (const float4*)E + (size_t)t * 2;
  float4 v0 = s4[0], v1 = s4[1];
  short8 o;
  o[0] = (short)f2bf(v0.x * SCALE_HALF); o[1] = (short)f2bf(v0.y * SCALE_HALF);
  o[2] = (short)f2bf(v0.z * SCALE_HALF); o[3] = (short)f2bf(v0.w * SCALE_HALF);
  o[4] = (short)f2bf(v1.x * SCALE_HALF); o[5] = (short)f2bf(v1.y * SCALE_HALF);
  o[6] = (short)f2bf(v1.z * SCALE_HALF); o[7] = (short)f2bf(v1.w * SCALE_HALF);
  *(short8*)(Eb + (size_t)t * 8) = o;
  if (t < B_TOTAL) {
    int4 l = ((const int4*)lab)[t];   // labels arrive as int32
    // positional one-hot: aspect a (value 0..5) occupies bits [6a, 6a+6)
    plab[t] = (1u << ((unsigned)l.x & 31u))
            | (1u << (((unsigned)l.y & 31u) + 6u))
            | (1u << (((unsigned)l.z & 31u) + 12u))
            | (1u << (((unsigned)l.w & 31u) + 18u));
  }
  if (t < 2 * B_TOTAL) posAll[t] = 0.0f;   // posArr+allArr contiguous
  if (t < NTILE * NTILE) {                 // forward-map triangle LUT
    const int I = t >> 6, J = t & 63;
    if (J >= I) {
      const int idx = I * NTILE - (I * (I - 1)) / 2 + (J - I);
      lut[idx] = ((unsigned)I << 8) | (unsigned)J;
    }
  }
}

// ---- fused tile kernel: one 128x128 tile per block, symmetric scatter -------
struct __align__(16) SMem {
  char btile[TILE * DDIM * 2];     // 64 KB, XOR-swizzled 16B chunks
  unsigned int plab_col[TILE];     // packed labels of the tile's columns
};

template <int DIAG>
__device__ __forceinline__ void compute_tile(
    const char* btile, const unsigned int* plab_col,
    const short8 (&afrag)[2][8], const unsigned int (&pi)[2][4],
    int l15, int l4, int wid, int colbase,
    float* posArr, float* allArr,
    f32x2 (&pos2)[2][2], f32x2 (&all2)[2][2]) {
#pragma unroll
  for (int nq = 0; nq < 4; ++nq) {     // 4 column-quarters of 32
    f32x4 acc[2][2];
#pragma unroll
    for (int n2 = 0; n2 < 2; ++n2)
#pragma unroll
      for (int m = 0; m < 2; ++m) acc[n2][m] = (f32x4){0.f, 0.f, 0.f, 0.f};

    __builtin_amdgcn_s_setprio(1);
#pragma unroll
    for (int k = 0; k < 8; ++k) {
      short8 b[2];
#pragma unroll
      for (int n2 = 0; n2 < 2; ++n2) {
        const unsigned int rr = (unsigned int)(nq * 32 + n2 * 16 + l15);
        const unsigned int s = (unsigned int)(k * 4 + l4) ^ (rr & 7u);
        b[n2] = *(const short8*)(btile + rr * 512u + s * 16u);
      }
#pragma unroll
      for (int n2 = 0; n2 < 2; ++n2)
#pragma unroll
        for (int m = 0; m < 2; ++m)
          acc[n2][m] = __builtin_amdgcn_mfma_f32_16x16x32_bf16(
              afrag[m][k], b[n2], acc[n2][m], 0, 0, 0);
    }
    __builtin_amdgcn_s_setprio(0);

    float colp[2] = {0.f, 0.f}, cola[2] = {0.f, 0.f};
#pragma unroll
    for (int n2 = 0; n2 < 2; ++n2) {
      const int jloc = nq * 32 + n2 * 16 + l15;   // column within tile
      const unsigned int hj = plab_col[jloc];
#pragma unroll
      for (int m = 0; m < 2; ++m) {
        float e[4];
#pragma unroll
        for (int q = 0; q < 4; ++q) {
          float v = __builtin_amdgcn_exp2f(acc[n2][m][q]);  // acc pre-scaled
          if (DIAG) { if (jloc == wid * 32 + m * 16 + l4 * 4 + q) v = 0.0f; }
          e[q] = v;
        }
        f32x2 p01 = { (pi[m][0] & hj) ? e[0] : 0.f, (pi[m][1] & hj) ? e[1] : 0.f };
        f32x2 p23 = { (pi[m][2] & hj) ? e[2] : 0.f, (pi[m][3] & hj) ? e[3] : 0.f };
        all2[m][0] += (f32x2){e[0], e[1]};
        all2[m][1] += (f32x2){e[2], e[3]};
        pos2[m][0] += p01;
        pos2[m][1] += p23;
        if (!DIAG) {   // column sums feed the mirrored (J,I) tile's rows
          cola[n2] += (e[0] + e[1]) + (e[2] + e[3]);
          colp[n2] += (p01[0] + p01[1]) + (p23[0] + p23[1]);
        }
      }
    }
    if (!DIAG) {
      // reduce the 4 row-subgroups (lanes ^16,^32) -> per-column wave totals
#pragma unroll
      for (int n2 = 0; n2 < 2; ++n2) {
        float cp = colp[n2], ca = cola[n2];
        cp += __shfl_xor(cp, 16); cp += __shfl_xor(cp, 32);
        ca += __shfl_xor(ca, 16); ca += __shfl_xor(ca, 32);
        if (l4 == 0) {
          atomicAdd(&posArr[colbase + nq * 32 + n2 * 16 + l15], cp);
          atomicAdd(&allArr[colbase + nq * 32 + n2 * 16 + l15], ca);
        }
      }
    }
  }
}

__global__ __launch_bounds__(256, 2) void main_kernel(
    const unsigned short* __restrict__ Eb, const unsigned int* __restrict__ plab,
    const unsigned int* __restrict__ lut,
    float* __restrict__ posArr, float* __restrict__ allArr) {
  __shared__ SMem sm;
  const int tid = threadIdx.x;
  const int lane = tid & 63;
  const int wid = tid >> 6;        // 4 waves, each owns 32 rows
  const int l15 = lane & 15;
  const int l4 = lane >> 4;
  const unsigned int pair = lut[blockIdx.x];
  const int I = (int)(pair >> 8), J = (int)(pair & 255u);
  const int rowbase = I * TILE;
  const int colbase = J * TILE;
  const int row0 = rowbase + wid * 32 + l4 * 4;   // +m*16+q = this lane's rows

  // stage the column tile: 64 KB, 16 x global_load_lds(16B) per thread.
  // linear LDS dest (wave-uniform base + lane*16), inverse-swizzled global src
  // (rule #21); read side applies the same XOR.
#pragma unroll
  for (int q = 0; q < 16; ++q) {
    const unsigned int L = (unsigned int)wid * 16384u + (unsigned int)q * 1024u +
                           (unsigned int)lane * 16u;
    const unsigned int r = L >> 9;          // tile column (0..127)
    const unsigned int s = (L >> 4) & 31u;  // stored 16B chunk in row
    const unsigned int c = s ^ (r & 7u);    // logical chunk (involution)
    const char* src = (const char*)(Eb + (size_t)(colbase + (int)r) * DDIM + c * 8);
    char* dst = sm.btile + (unsigned int)wid * 16384u + (unsigned int)q * 1024u;
    __builtin_amdgcn_global_load_lds((gbl_char*)src, (lds_char*)dst, 16, 0, 0);
  }

  // A fragments: register-resident, 32 rows x 256 k per wave (64 VGPR)
  short8 afrag[2][8];
#pragma unroll
  for (int m = 0; m < 2; ++m) {
    const int row = rowbase + wid * 32 + m * 16 + l15;
    const unsigned short* rp = Eb + (size_t)row * DDIM + l4 * 8;
#pragma unroll
    for (int k = 0; k < 8; ++k) afrag[m][k] = *(const short8*)(rp + k * 32);
  }

  if (tid < TILE) sm.plab_col[tid] = plab[colbase + tid];

  unsigned int pi[2][4];
#pragma unroll
  for (int m = 0; m < 2; ++m)
#pragma unroll
    for (int q = 0; q < 4; ++q) pi[m][q] = plab[row0 + m * 16 + q];

  asm volatile("s_waitcnt vmcnt(0) lgkmcnt(0)" ::: "memory");
  __builtin_amdgcn_s_barrier();
  __builtin_amdgcn_sched_barrier(0);

  f32x2 pos2[2][2] = {};
  f32x2 all2[2][2] = {};

  if (I == J)
    compute_tile<1>(sm.btile, sm.plab_col, afrag, pi, l15, l4, wid, colbase,
                    posArr, allArr, pos2, all2);
  else
    compute_tile<0>(sm.btile, sm.plab_col, afrag, pi, l15, l4, wid, colbase,
                    posArr, allArr, pos2, all2);

  // row-side: reduce across the 16 lanes sharing rows, one atomic per row
#pragma unroll
  for (int m = 0; m < 2; ++m)
#pragma unroll
    for (int q = 0; q < 4; ++q) {
      float p = pos2[m][q >> 1][q & 1], al = all2[m][q >> 1][q & 1];
      p += __shfl_xor(p, 1); p += __shfl_xor(p, 2);
      p += __shfl_xor(p, 4); p += __shfl_xor(p, 8);
      al += __shfl_xor(al, 1); al += __shfl_xor(al, 2);
      al += __shfl_xor(al, 4); al += __shfl_xor(al, 8);
      if (l15 == 0) {
        atomicAdd(&posArr[row0 + m * 16 + q], p);
        atomicAdd(&allArr[row0 + m * 16 + q], al);
      }
    }
}

// ---- finalize: row losses + mean (separate launch = free ordering) ----------
__global__ __launch_bounds__(1024) void finalize_kernel(
    const float* __restrict__ posArr, const float* __restrict__ allArr,
    float* __restrict__ out) {
  float ls = 0.f, cnt = 0.f;
#pragma unroll
  for (int k = 0; k < B_TOTAL / 1024; ++k) {
    const int i = threadIdx.x + (k << 10);
    const float p = posArr[i];
    const float a = allArr[i];
    if (p > 0.f) {
      ls += (__builtin_amdgcn_logf(a + 1e-8f) - __builtin_amdgcn_logf(p)) * LN2F;
      cnt += 1.f;
    }
  }
#pragma unroll
  for (int msk = 1; msk < 64; msk <<= 1) {
    ls += __shfl_xor(ls, msk);
    cnt += __shfl_xor(cnt, msk);
  }
  __shared__ float sls[16], scnt[16];
  const int w = threadIdx.x >> 6;
  if ((threadIdx.x & 63) == 0) { sls[w] = ls; scnt[w] = cnt; }
  __syncthreads();
  if (threadIdx.x == 0) {
    float L = 0.f, C = 0.f;
    for (int i = 0; i < 16; ++i) { L += sls[i]; C += scnt[i]; }
    out[0] = (C > 0.f) ? L / fmaxf(C, 1.f) : 0.f;
  }
}

// ---- launch -----------------------------------------------------------------
extern "C" void kernel_launch(void* const* d_in, const int* in_sizes, int n_in,
                              void* d_out, int out_size, void* d_ws, size_t ws_size,
                              hipStream_t stream) {
  const float* E = (const float*)d_in[0];
  const int* lab = (const int*)d_in[1];
  float* out = (float*)d_out;
  char* ws = (char*)d_ws;

  unsigned short* Eb = (unsigned short*)ws;                       // 4 MB
  unsigned int* plab = (unsigned int*)(ws + 4u * 1024u * 1024u);  // 32 KB
  float* posArr = (float*)(ws + 4u * 1024u * 1024u + 32u * 1024u);
  float* allArr = posArr + B_TOTAL;                               // 64 KB both
  unsigned int* lut = (unsigned int*)(allArr + B_TOTAL);          // 8.3 KB

  prep_all<<<1024, 256, 0, stream>>>(E, lab, Eb, plab, posArr, lut);
  main_kernel<<<NPAIRS, 256, 0, stream>>>(Eb, plab, lut, posArr, allArr);
  finalize_kernel<<<1, 1024, 0, stream>>>(posArr, allArr, out);
}

// Round 9
// 112.041 us; speedup vs baseline: 1.1907x; 1.1277x over previous
//
#include <hip/hip_runtime.h>
#include <stdint.h>

typedef short short8 __attribute__((ext_vector_type(8)));
typedef float f32x4 __attribute__((ext_vector_type(4)));
typedef float f32x2 __attribute__((ext_vector_type(2)));

#define B_TOTAL 8192
#define DDIM 256
#define BM 256
#define BN 64
#define NSPLIT 16
#define COLS_PER (B_TOTAL / NSPLIT)        // 512
#define ITERS (COLS_PER / BN)              // 8
#define NBLOCKS ((B_TOTAL / BM) * NSPLIT)  // 512 blocks x 512 thr = 2 blocks/CU, 16 waves/CU
// sqrt((1/T)/ln2): fold temperature+log2e into the bf16 embeddings (both operands)
#define SCALE_HALF 3.79828546f
#define LN2F 0.6931471805599453f

typedef __attribute__((address_space(3))) char lds_char;
typedef __attribute__((address_space(1))) const char gbl_char;

__device__ __forceinline__ unsigned short f2bf(float f) {
  unsigned int u = __builtin_bit_cast(unsigned int, f);
  u = (u + 0x7FFFu + ((u >> 16) & 1u)) >> 16;   // RNE; inputs are finite
  return (unsigned short)u;
}

// ---- prep: fp32->bf16 (scaled), one-hot label pack, zero accumulators -------
__global__ __launch_bounds__(256) void prep_all(
    const float* __restrict__ E, const int* __restrict__ lab,
    unsigned short* __restrict__ Eb, unsigned int* __restrict__ plab,
    float* __restrict__ posAll) {
  const int t = blockIdx.x * 256 + threadIdx.x;   // 0..262143, 8 floats each
  const float4* s4 = (const float4*)E + (size_t)t * 2;
  float4 v0 = s4[0], v1 = s4[1];
  short8 o;
  o[0] = (short)f2bf(v0.x * SCALE_HALF); o[1] = (short)f2bf(v0.y * SCALE_HALF);
  o[2] = (short)f2bf(v0.z * SCALE_HALF); o[3] = (short)f2bf(v0.w * SCALE_HALF);
  o[4] = (short)f2bf(v1.x * SCALE_HALF); o[5] = (short)f2bf(v1.y * SCALE_HALF);
  o[6] = (short)f2bf(v1.z * SCALE_HALF); o[7] = (short)f2bf(v1.w * SCALE_HALF);
  *(short8*)(Eb + (size_t)t * 8) = o;
  if (t < B_TOTAL) {
    int4 l = ((const int4*)lab)[t];   // labels arrive as int32
    // positional one-hot: aspect a (value 0..5) occupies bits [6a, 6a+6)
    plab[t] = (1u << ((unsigned)l.x & 31u))
            | (1u << (((unsigned)l.y & 31u) + 6u))
            | (1u << (((unsigned)l.z & 31u) + 12u))
            | (1u << (((unsigned)l.w & 31u) + 18u));
  }
  if (t < 2 * B_TOTAL) posAll[t] = 0.0f;   // posArr+allArr contiguous
}

// ---- fused sim/exp/mask/rowsum: 8 waves x 32 rows, 2-phase dbuf -------------
struct __align__(16) SMem {
  char btile[2][BN * DDIM * 2];      // 2 x 32 KB, XOR-swizzled 16B chunks
  unsigned int plab_all[COLS_PER];   // 2 KB: packed labels for the whole panel
};

template <int DIAG>
__device__ __forceinline__ void do_epilogue(
    const f32x4 (&acc)[4][2], int colbase, int it, int l15,
    const unsigned int (&pi)[2][4], const int (&irow)[2][4],
    const unsigned int* plab_all, f32x2 (&pos2)[2][2], f32x2 (&all2)[2][2]) {
#pragma unroll
  for (int n = 0; n < 4; ++n) {
    const int j = colbase + n * 16 + l15;
    const unsigned int hj = plab_all[it * BN + n * 16 + l15];
#pragma unroll
    for (int m = 0; m < 2; ++m) {
      float e[4];
#pragma unroll
      for (int q = 0; q < 4; ++q) {
        float v = __builtin_amdgcn_exp2f(acc[n][m][q]);  // acc already scaled
        if (DIAG) { if (j == irow[m][q]) v = 0.0f; }
        e[q] = v;
      }
      f32x2 p01 = { (pi[m][0] & hj) ? e[0] : 0.0f, (pi[m][1] & hj) ? e[1] : 0.0f };
      f32x2 p23 = { (pi[m][2] & hj) ? e[2] : 0.0f, (pi[m][3] & hj) ? e[3] : 0.0f };
      all2[m][0] += (f32x2){e[0], e[1]};
      all2[m][1] += (f32x2){e[2], e[3]};
      pos2[m][0] += p01;
      pos2[m][1] += p23;
    }
  }
}

__global__ __launch_bounds__(512, 2) void main_kernel(
    const unsigned short* __restrict__ Eb, const unsigned int* __restrict__ plab,
    float* __restrict__ posArr, float* __restrict__ allArr) {
  __shared__ SMem sm;
  const int tid = threadIdx.x;
  const int lane = tid & 63;
  const int wid = tid >> 6;        // 8 waves, each owns 32 rows
  const int l15 = lane & 15;
  const int l4 = lane >> 4;
  const int rb = (int)blockIdx.x & 31;   // 32 row-blocks of 256
  const int cs = (int)blockIdx.x >> 5;   // 16 column panels of 512
  const int rowbase = rb * BM;
  const int colstart = cs * COLS_PER;

  // stage helper: 32 KB tile, 4 x global_load_lds(16B) per thread (512 thr).
  // linear LDS dest (wave-uniform base + lane*16), inverse-swizzled global src
  // (rule #21); read side applies the same XOR.
  auto stage = [&](int bufi, int cb) {
#pragma unroll
    for (int q = 0; q < 4; ++q) {
      const unsigned int base = (unsigned int)q * 8192u + (unsigned int)wid * 1024u;
      const unsigned int L = base + (unsigned int)lane * 16u;
      const unsigned int r = L >> 9;          // B-tile row / output column (0..63)
      const unsigned int s = (L >> 4) & 31u;  // stored 16B chunk in row
      const unsigned int c = s ^ (r & 7u);    // logical chunk (involution)
      const char* src = (const char*)(Eb + (size_t)(cb + (int)r) * DDIM + c * 8);
      char* dst = sm.btile[bufi] + base;
      __builtin_amdgcn_global_load_lds((gbl_char*)src, (lds_char*)dst, 16, 0, 0);
    }
  };

  // prologue: issue tile 0 staging first (hide L2 latency under setup below)
  stage(0, colstart);

  // A fragments: register-resident, 32 rows x 256 k per wave (64 VGPR)
  short8 afrag[2][8];
#pragma unroll
  for (int m = 0; m < 2; ++m) {
    const int row = rowbase + wid * 32 + m * 16 + l15;
    const unsigned short* rp = Eb + (size_t)row * DDIM + l4 * 8;
#pragma unroll
    for (int k = 0; k < 8; ++k) afrag[m][k] = *(const short8*)(rp + k * 32);
  }

  // panel labels -> LDS once (keeps the in-loop vmcnt count pure: stage only)
  sm.plab_all[tid] = plab[colstart + tid];

  unsigned int pi[2][4];
  int irow[2][4];
#pragma unroll
  for (int m = 0; m < 2; ++m)
#pragma unroll
    for (int q = 0; q < 4; ++q) {
      const int i = rowbase + wid * 32 + m * 16 + l4 * 4 + q;
      irow[m][q] = i;
      pi[m][q] = plab[i];
    }

  // drain label ds_writes before first barrier (other waves read plab_all)
  asm volatile("s_waitcnt lgkmcnt(0)" ::: "memory");
  __builtin_amdgcn_sched_barrier(0);

  f32x2 pos2[2][2] = {};
  f32x2 all2[2][2] = {};

  for (int it = 0; it < ITERS; ++it) {
    const int colbase = colstart + it * BN;
    const int cur = it & 1;

    if (it + 1 < ITERS) {
      stage(cur ^ 1, colbase + BN);                     // issue next tile (4/thread)
      asm volatile("s_waitcnt vmcnt(4)" ::: "memory");  // oldest 4 (tile it) landed
    } else {
      asm volatile("s_waitcnt vmcnt(0)" ::: "memory");  // final tile: full drain
    }
    __builtin_amdgcn_s_barrier();                       // all waves' shares landed
    __builtin_amdgcn_sched_barrier(0);

    f32x4 acc[4][2];
#pragma unroll
    for (int n = 0; n < 4; ++n)
#pragma unroll
      for (int m = 0; m < 2; ++m) acc[n][m] = (f32x4){0.f, 0.f, 0.f, 0.f};

    __builtin_amdgcn_s_setprio(1);
#pragma unroll
    for (int k = 0; k < 8; ++k) {
      short8 b[4];
#pragma unroll
      for (int n = 0; n < 4; ++n) {
        const unsigned int rr = (unsigned int)(n * 16 + l15);
        const unsigned int cdx = (unsigned int)(k * 4 + l4);
        const unsigned int s = cdx ^ (rr & 7u);   // swizzled read
        b[n] = *(const short8*)(sm.btile[cur] + rr * 512u + s * 16u);
      }
#pragma unroll
      for (int n = 0; n < 4; ++n)
#pragma unroll
        for (int m = 0; m < 2; ++m)
          acc[n][m] = __builtin_amdgcn_mfma_f32_16x16x32_bf16(
              afrag[m][k], b[n], acc[n][m], 0, 0, 0);
    }
    __builtin_amdgcn_s_setprio(0);

    const bool hasDiag = (colbase < rowbase + BM) && (rowbase < colbase + BN);
    if (hasDiag)
      do_epilogue<1>(acc, colbase, it, l15, pi, irow, sm.plab_all, pos2, all2);
    else
      do_epilogue<0>(acc, colbase, it, l15, pi, irow, sm.plab_all, pos2, all2);

    __builtin_amdgcn_s_barrier();   // all waves done reading btile[cur]
    __builtin_amdgcn_sched_barrier(0);
  }

  // reduce across the 16 lanes sharing the same rows, then one atomic per row
#pragma unroll
  for (int m = 0; m < 2; ++m)
#pragma unroll
    for (int q = 0; q < 4; ++q) {
      float p = pos2[m][q >> 1][q & 1], al = all2[m][q >> 1][q & 1];
      p += __shfl_xor(p, 1); p += __shfl_xor(p, 2);
      p += __shfl_xor(p, 4); p += __shfl_xor(p, 8);
      al += __shfl_xor(al, 1); al += __shfl_xor(al, 2);
      al += __shfl_xor(al, 4); al += __shfl_xor(al, 8);
      if (l15 == 0) {
        atomicAdd(&posArr[irow[m][q]], p);
        atomicAdd(&allArr[irow[m][q]], al);
      }
    }
}

// ---- finalize: row losses + mean (separate launch = free ordering) ----------
__global__ __launch_bounds__(1024) void finalize_kernel(
    const float* __restrict__ posArr, const float* __restrict__ allArr,
    float* __restrict__ out) {
  float ls = 0.f, cnt = 0.f;
#pragma unroll
  for (int k = 0; k < B_TOTAL / 1024; ++k) {
    const int i = threadIdx.x + (k << 10);
    const float p = posArr[i];
    const float a = allArr[i];
    if (p > 0.f) {
      ls += (__builtin_amdgcn_logf(a + 1e-8f) - __builtin_amdgcn_logf(p)) * LN2F;
      cnt += 1.f;
    }
  }
#pragma unroll
  for (int msk = 1; msk < 64; msk <<= 1) {
    ls += __shfl_xor(ls, msk);
    cnt += __shfl_xor(cnt, msk);
  }
  __shared__ float sls[16], scnt[16];
  const int w = threadIdx.x >> 6;
  if ((threadIdx.x & 63) == 0) { sls[w] = ls; scnt[w] = cnt; }
  __syncthreads();
  if (threadIdx.x == 0) {
    float L = 0.f, C = 0.f;
    for (int i = 0; i < 16; ++i) { L += sls[i]; C += scnt[i]; }
    out[0] = (C > 0.f) ? L / fmaxf(C, 1.f) : 0.f;
  }
}

// ---- launch -----------------------------------------------------------------
extern "C" void kernel_launch(void* const* d_in, const int* in_sizes, int n_in,
                              void* d_out, int out_size, void* d_ws, size_t ws_size,
                              hipStream_t stream) {
  const float* E = (const float*)d_in[0];
  const int* lab = (const int*)d_in[1];
  float* out = (float*)d_out;
  char* ws = (char*)d_ws;

  unsigned short* Eb = (unsigned short*)ws;                       // 4 MB
  unsigned int* plab = (unsigned int*)(ws + 4u * 1024u * 1024u);  // 32 KB
  float* posArr = (float*)(ws + 4u * 1024u * 1024u + 32u * 1024u);
  float* allArr = posArr + B_TOTAL;

  prep_all<<<1024, 256, 0, stream>>>(E, lab, Eb, plab, posArr);
  main_kernel<<<NBLOCKS, 512, 0, stream>>>(Eb, plab, posArr, allArr);
  finalize_kernel<<<1, 1024, 0, stream>>>(posArr, allArr, out);
}